// Round 4
// baseline (91.300 us; speedup 1.0000x reference)
//
#include <hip/hip_runtime.h>
#include <hip/hip_bf16.h>

#define BB 16
#define SS 2048
#define DD 1024
#define HH 16
#define KK 31
#define HK 496

typedef float f32x4 __attribute__((ext_vector_type(4)));
typedef __bf16 bf16x8 __attribute__((ext_vector_type(8)));

__device__ __forceinline__ unsigned short f2bf(float x) {
  unsigned u = __float_as_uint(x);
  unsigned r = u + 0x7FFFu + ((u >> 16) & 1u);
  return (unsigned short)(r >> 16);
}

// ---------------- prep: W_q (f32, D x 496) -> bf16 image, padded N=512.
// Layout for direct per-wave fragment loads:
// Bimg[ks][w][n][g][qq][e] = W[k=ks*32+g*8+e][col=w*64+n*16+qq]
__global__ void prep_kernel(const float* __restrict__ Wq,
                            unsigned short* __restrict__ Bimg) {
  int idx = blockIdx.x * 256 + threadIdx.x;  // < 32*8*4*4*16*8 = 524288
  int e = idx & 7;
  int qq = (idx >> 3) & 15;
  int g = (idx >> 7) & 3;
  int n = (idx >> 9) & 3;
  int w = (idx >> 11) & 7;
  int ks = idx >> 14;
  int k = ks * 32 + g * 8 + e;
  int c = w * 64 + n * 16 + qq;
  int h = c >> 5, j = c & 31;
  float v = (j < KK) ? Wq[k * HK + h * KK + j] : 0.f;
  Bimg[idx] = f2bf(v);
}

// ---------------- ksum: (B,S,H) = sum over 64 channels per head, f32
__global__ void ksum_kernel(const float* __restrict__ key,
                            float* __restrict__ ksum) {
  const int row = blockIdx.x;   // b*S + s
  const int tid = threadIdx.x;  // 0..255, 4 channels each
  const float4 v = reinterpret_cast<const float4*>(key + (size_t)row * DD)[tid];
  float p = v.x + v.y + v.z + v.w;
  p += __shfl_xor(p, 1);
  p += __shfl_xor(p, 2);
  p += __shfl_xor(p, 4);
  p += __shfl_xor(p, 8);
  if ((tid & 15) == 0) ksum[(size_t)row * HH + (tid >> 4)] = p;
}

// ---------------- fused GEMM (bf16 MFMA) + per-position conv + transpose
// BM=64, BN=512, 8 waves. Phase 1: stage FULL A tile (64x1024) from q with
// LINEAR global reads into 128KB LDS image [ks][g][row] (XOR-swizzled).
// Phase 2: 32 K-steps, no barriers; B fragments direct from L2 per wave.
__global__ __launch_bounds__(512, 2) void mca_kernel(
    const float* __restrict__ q, const float* __restrict__ bq,
    const float* __restrict__ convb, const float* __restrict__ ksum,
    const unsigned short* __restrict__ Bimg, float* __restrict__ out) {
  extern __shared__ char smem[];
  const int tid = threadIdx.x;
  const int w = tid >> 6, lane = tid & 63;
  const int g = lane >> 4, qq = lane & 15;
  const int bid = blockIdx.x;
  const int bb = bid >> 5;
  const int t0 = (bid & 31) << 6;

  const float* qblk = q + ((size_t)(bb * SS + t0)) * DD;
  // per-wave B fragment stream base (16B per lane, 1KB per (n))
  const unsigned short* bbase = Bimg + w * 2048 + lane * 8;

  f32x4 acc[4][4];
#pragma unroll
  for (int m = 0; m < 4; ++m)
#pragma unroll
    for (int n = 0; n < 4; ++n) acc[m][n] = (f32x4){0.f, 0.f, 0.f, 0.f};

  // ---- Phase 1: linear stage of the whole 256KB q-slice -> bf16 LDS image
  // granule gidx (16B of f32 = 4 k-elems): row = gidx>>8, c16 = gidx&255
  // k-granule c16 -> (ks = c16>>3, g = (c16>>1)&3, half = c16&1)
  // physical byte = (ks*4096 + g*1024 + row*16 + half*8) ^ ((ks&7)<<4)
#pragma unroll 8
  for (int it = 0; it < 32; ++it) {
    const int gidx = it * 512 + tid;
    const int row = gidx >> 8;
    const int c16 = gidx & 255;
    const float4 v = reinterpret_cast<const float4*>(qblk)[gidx];
    const int ks = c16 >> 3, gg = (c16 >> 1) & 3, half = c16 & 1;
    const unsigned u0 = (unsigned)f2bf(v.x) | ((unsigned)f2bf(v.y) << 16);
    const unsigned u1 = (unsigned)f2bf(v.z) | ((unsigned)f2bf(v.w) << 16);
    const int byte = (ks * 4096 + gg * 1024 + row * 16 + half * 8) ^ ((ks & 7) << 4);
    *reinterpret_cast<uint2*>(smem + byte) = make_uint2(u0, u1);
  }
  __syncthreads();

  // ---- Phase 2: 32 K-steps, no barriers
  auto loadB = [&](int ks, bf16x8* pB) {
    const unsigned short* p = bbase + (size_t)ks * 16384;
#pragma unroll
    for (int n = 0; n < 4; ++n)
      pB[n] = *reinterpret_cast<const bf16x8*>(p + n * 512);
  };
  auto compute = [&](int ks, const bf16x8* pB) {
    const int sw = (ks & 7) << 4;
    bf16x8 af[4];
#pragma unroll
    for (int m = 0; m < 4; ++m) {
      const int byte = (ks * 4096 + g * 1024 + (m * 16 + qq) * 16) ^ sw;
      af[m] = *reinterpret_cast<const bf16x8*>(smem + byte);
    }
#pragma unroll
    for (int m = 0; m < 4; ++m)
#pragma unroll
      for (int n = 0; n < 4; ++n)
        acc[m][n] = __builtin_amdgcn_mfma_f32_16x16x32_bf16(af[m], pB[n], acc[m][n], 0, 0, 0);
  };

  bf16x8 pBa[4], pBb[4];
  loadB(0, pBa);
#pragma unroll
  for (int k2 = 0; k2 < 16; ++k2) {
    loadB(2 * k2 + 1, pBb);
    compute(2 * k2, pBa);
    if (k2 < 15) loadB(2 * k2 + 2, pBa);
    compute(2 * k2 + 1, pBb);
  }

  // ---- epilogue: conv over j (K=31) in f32 ----
  float bqv[4];
#pragma unroll
  for (int n = 0; n < 4; ++n) {
    int c = w * 64 + n * 16 + qq;
    int h = c >> 5, j = c & 31;
    bqv[n] = (j < KK) ? bq[h * KK + j] : 0.f;
  }
  float cb[2] = {convb[w * 2], convb[w * 2 + 1]};

  __syncthreads();  // A image dead; reuse smem for ksum slice
  float* kl = reinterpret_cast<float*>(smem);
  for (int i = tid; i < 96 * 16; i += 512) {
    int trow = i >> 4, h = i & 15;
    int t = t0 + trow - 15;
    kl[trow * 17 + h] = (t >= 0 && t < SS) ? ksum[((size_t)bb * SS + t) * HH + h] : 0.f;
  }
  __syncthreads();

#pragma unroll
  for (int m = 0; m < 4; ++m) {
    float part[4][2];
#pragma unroll
    for (int r = 0; r < 4; ++r) {
      part[r][0] = 0.f;
      part[r][1] = 0.f;
    }
#pragma unroll
    for (int n = 0; n < 4; ++n) {
      const int hp = n >> 1;
      const int j = (n & 1) * 16 + qq;  // j==31 has zero weight (padded col)
      const int h = w * 2 + hp;
#pragma unroll
      for (int r = 0; r < 4; ++r) {
        const int tl = m * 16 + g * 4 + r;
        part[r][hp] += (acc[m][n][r] + bqv[n]) * kl[(tl + j) * 17 + h];
      }
    }
#pragma unroll
    for (int r = 0; r < 4; ++r)
#pragma unroll
      for (int hp = 0; hp < 2; ++hp) {
        float v = part[r][hp];
        v += __shfl_xor(v, 1);
        v += __shfl_xor(v, 2);
        v += __shfl_xor(v, 4);
        v += __shfl_xor(v, 8);
        part[r][hp] = v;
      }
    if (qq < 4) {
      const int r = qq;
      const int t = t0 + m * 16 + g * 4 + r;
#pragma unroll
      for (int hp = 0; hp < 2; ++hp)
        out[((size_t)bb * HH + w * 2 + hp) * SS + t] = part[r][hp] + cb[hp];
    }
  }
}

extern "C" void kernel_launch(void* const* d_in, const int* in_sizes, int n_in,
                              void* d_out, int out_size, void* d_ws, size_t ws_size,
                              hipStream_t stream) {
  const float* q   = (const float*)d_in[0];
  const float* key = (const float*)d_in[1];
  // d_in[2] (values) and d_in[3] (lengths) are unused by the reference
  const float* Wq  = (const float*)d_in[4];
  const float* bq  = (const float*)d_in[5];
  const float* cvb = (const float*)d_in[6];
  float* out = (float*)d_out;

  float* ksum = (float*)d_ws;                                        // 2 MB f32
  unsigned short* Bimg = (unsigned short*)((char*)d_ws + 2097152);   // 1 MB bf16

  hipFuncSetAttribute((const void*)mca_kernel,
                      hipFuncAttributeMaxDynamicSharedMemorySize, 131072);

  prep_kernel<<<2048, 256, 0, stream>>>(Wq, Bimg);
  ksum_kernel<<<BB * SS, 256, 0, stream>>>(key, ksum);
  mca_kernel<<<BB * (SS / 64), 512, 131072, stream>>>(q, bq, cvb, ksum, Bimg, out);
}